// Round 9
// baseline (158.086 us; speedup 1.0000x reference)
//
#include <hip/hip_runtime.h>

// Problem constants (B=8, Tq=Tv=512, D=512, U=128)
constexpr int Bb = 8;
constexpr int Tq = 512;
constexpr int Tv = 512;
constexpr int Dd = 512;
constexpr int Uu = 128;
constexpr float C2LOG2E = 2.88539008177792681f;   // 2*log2(e)

typedef float v2f __attribute__((ext_vector_type(2)));

// ---------------------------------------------------------------------------
// Kernel A v9: projections. 8 rows/block, 512 threads, 1024 blocks.
// LATENCY-TOLERANT rebuild: x staged in LDS (coalesced float4, wave-uniform
// broadcast reads in the K-loop), __launch_bounds__(512,6) -> VGPR cap 84
// (3 blocks/CU, 24 waves) giving the scheduler register room to hoist loads,
// and unroll 4 on the K-loop for deep software pipelining of the W stream.
// Outputs Eq/Ek = exp2(2log2e * proj); kT compact u4-interleaved.
// The j0==0 key-block exports the mask scan (jl_g, cnt_g).
// ---------------------------------------------------------------------------
__global__ __launch_bounds__(512, 6) void proj_kernel(
    const float* __restrict__ query,
    const float* __restrict__ key,
    const float* __restrict__ Wa,
    const float* __restrict__ Ua,
    const int* __restrict__ mask,
    float* __restrict__ qf2, float* __restrict__ kT,
    int* __restrict__ jl_g, int* __restrict__ cnt_g)
{
    const int R    = blockIdx.x * 8;               // 0..8191
    const bool isQ = R < Bb * Tq;
    const float* __restrict__ src = isQ ? query : key;
    const float* __restrict__ W   = isQ ? Wa : Ua;
    const int Rloc = isQ ? R : R - Bb * Tq;        // 0..4095

    __shared__ float smem[8 * 8 * 128];            // 32 KB: x[8][512] then part[8][8][128]
    __shared__ int posLoc[8];
    float* __restrict__ x = smem;
    const int t = threadIdx.x;

    {   // stage 8 rows: 1024 float4, coalesced, 2/thread
        const float4* __restrict__ s4 =
            reinterpret_cast<const float4*>(src + (size_t)Rloc * Dd);
        float4* x4 = reinterpret_cast<float4*>(x);
        x4[t]       = s4[t];
        x4[t + 512] = s4[t + 512];
    }
    if (!isQ && t < 64) {                          // wave-0 ballot scan -> pos
        const int b  = Rloc >> 9;
        const int j0 = Rloc & 511;                 // 8-aligned
        const bool writer = (j0 == 0);             // one block per batch exports
        int base = 0;
#pragma unroll
        for (int c = 0; c < 8; ++c) {
            const int j = c * 64 + t;
            const int v = (mask[b * 512 + j] != 0);
            const unsigned long long bits = __ballot(v);
            const int pos = base + (int)__popcll(bits & ((1ull << t) - 1ull));
            if (j >= j0 && j < j0 + 8) posLoc[j - j0] = v ? pos : -1;
            if (writer && v) jl_g[b * 512 + pos] = j;
            base += (int)__popcll(bits);
        }
        if (writer && t == 0) cnt_g[b] = base;
    }
    __syncthreads();

    const int u2 = (t & 63) * 2;                   // adjacent u pair
    const int dq = t >> 6;                         // wave-owned d-eighth 0..7
    const float* __restrict__ Wq = W + (size_t)dq * 64 * Uu;
    const float* __restrict__ xq = x + dq * 64;

    float acc[8][2];
#pragma unroll
    for (int r = 0; r < 8; ++r) { acc[r][0] = 0.f; acc[r][1] = 0.f; }

#pragma unroll 4
    for (int d4 = 0; d4 < 16; ++d4) {
        const int d = d4 * 4;
        const float2 w0 = *reinterpret_cast<const float2*>(Wq + (d + 0) * Uu + u2);
        const float2 w1 = *reinterpret_cast<const float2*>(Wq + (d + 1) * Uu + u2);
        const float2 w2 = *reinterpret_cast<const float2*>(Wq + (d + 2) * Uu + u2);
        const float2 w3 = *reinterpret_cast<const float2*>(Wq + (d + 3) * Uu + u2);
#pragma unroll
        for (int r = 0; r < 8; ++r) {
            const float4 xv = *reinterpret_cast<const float4*>(xq + r * Dd + d); // LDS broadcast
            acc[r][0] = fmaf(xv.x, w0.x, acc[r][0]);
            acc[r][1] = fmaf(xv.x, w0.y, acc[r][1]);
            acc[r][0] = fmaf(xv.y, w1.x, acc[r][0]);
            acc[r][1] = fmaf(xv.y, w1.y, acc[r][1]);
            acc[r][0] = fmaf(xv.z, w2.x, acc[r][0]);
            acc[r][1] = fmaf(xv.z, w2.y, acc[r][1]);
            acc[r][0] = fmaf(xv.w, w3.x, acc[r][0]);
            acc[r][1] = fmaf(xv.w, w3.y, acc[r][1]);
        }
    }

    __syncthreads();                               // all waves done reading x
    {
        float* __restrict__ part = smem;           // alias over x: part[dq][r][u]
#pragma unroll
        for (int r = 0; r < 8; ++r) {              // float2, 2-way bank alias: free
            float2 p; p.x = acc[r][0]; p.y = acc[r][1];
            *reinterpret_cast<float2*>(part + (dq * 8 + r) * 128 + u2) = p;
        }
    }
    __syncthreads();

    // reduce 8 d-partials, apply exp2(2log2e * .), store.
    // thread -> row r = t>>6, u0 = (t&63)*2
    {
        const float* __restrict__ part = smem;
        const int r  = t >> 6;
        const int u0 = (t & 63) * 2;
        float s0 = 0.f, s1 = 0.f;
#pragma unroll
        for (int p = 0; p < 8; ++p) {
            const float2 pv = *reinterpret_cast<const float2*>(part + (p * 8 + r) * 128 + u0);
            s0 += pv.x;
            s1 += pv.y;
        }
        float2 e;
        e.x = __builtin_amdgcn_exp2f(C2LOG2E * s0);
        e.y = __builtin_amdgcn_exp2f(C2LOG2E * s1);
        if (isQ) {
            *reinterpret_cast<float2*>(qf2 + (size_t)(Rloc + r) * Uu + u0) = e;
        } else {
            const int p = posLoc[r];
            if (p >= 0) {
                float* __restrict__ kb = kT + (size_t)(Rloc >> 9) * Uu * Tv;
                const int u4 = u0 >> 2;            // quad index
                const int c  = u0 & 3;             // 0 or 2
                *reinterpret_cast<float2*>(kb + ((size_t)u4 * Tv + p) * 4 + c) = e;
            }
        }
    }
}

// ---------------------------------------------------------------------------
// Kernel B v7 (EXACT R6 body -- best measured, 57.6 us): attention over
// COMPACT exp-keys. 4 query rows/block, 512 threads, 1024 blocks, bijective
// XCD swizzle. Score: pk-fp32 + quad-rcp, scalar q/scale. Softmax: no max
// pass. Context: 4 d's/thread, 4 wave-uniform j-groups, pk_fma.
// ---------------------------------------------------------------------------
__global__ __launch_bounds__(512, 8) void attn_kernel(
    const float* __restrict__ qf2, const float* __restrict__ kT,
    const float* __restrict__ value,
    const int* __restrict__ jl_g, const int* __restrict__ cnt_g,
    const float* __restrict__ scale,
    float* __restrict__ out)
{
    // XCD-aware bijective swizzle (1024 % 8 == 0): XCD x <-> batch x
    const int bid = blockIdx.x;
    const int swz = (bid & 7) * 128 + (bid >> 3);
    const int r0 = swz * 4;                   // first query row (0..4092)
    const int b  = r0 >> 9;
    const int t  = threadIdx.x;               // 0..511

    __shared__ int   jl[Tv];                  // 2 KB
    __shared__ float w[4 * Tv];               // 8 KB (u-half-0 partials -> weights)
    __shared__ float pbuf[12 * Dd];           // 24 KB (score u-half-1; context partials)
    __shared__ float sums8[8];                // per (row, half) exp-sums

    const int cnt = cnt_g[b];                 // uniform -> s_load
    jl[t] = (t < cnt) ? jl_g[b * 512 + t] : 0;
    // no barrier: score reads no LDS; jl consumed after 2 barriers

    const int wvu = __builtin_amdgcn_readfirstlane(t >> 6); // wave id, SGPR
    const int cntp4 = (cnt + 3) & ~3;

    // ---- scores: 2 u-half groups x 256 compact-j lanes, pk + quad-rcp ----
    {
        const int g   = wvu >> 2;             // u-half (waves 0-3 -> 0, 4-7 -> 1)
        const int jc0 = t & 255;
        const float* __restrict__ qs = qf2 + (size_t)r0 * Uu + g * 64;  // uniform
        const float* __restrict__ ss = scale + g * 64;                  // uniform
        const float4* __restrict__ kb4 =
            reinterpret_cast<const float4*>(kT) + (size_t)b * 32 * Tv + (size_t)g * 16 * Tv;
        float* __restrict__ wr = g ? pbuf : w;
        for (int jb = 0; jb < cnt; jb += 256) {
            const int jc = jb + jc0;
            if (jc < cnt) {
                v2f acc2[4];
#pragma unroll
                for (int i = 0; i < 4; ++i) acc2[i] = (v2f){0.f, 0.f};
#pragma unroll 4
                for (int u4 = 0; u4 < 16; ++u4) {
                    const float4 kv = kb4[(size_t)u4 * Tv + jc];
                    const v2f kv01 = {kv.x, kv.y};
                    const v2f kv23 = {kv.z, kv.w};
                    const v2f sv01 = *reinterpret_cast<const v2f*>(ss + u4 * 4);
                    const v2f sv23 = *reinterpret_cast<const v2f*>(ss + u4 * 4 + 2);
#pragma unroll
                    for (int i = 0; i < 4; ++i) {
                        const v2f qv01 = *reinterpret_cast<const v2f*>(qs + i * Uu + u4 * 4);
                        const v2f qv23 = *reinterpret_cast<const v2f*>(qs + i * Uu + u4 * 4 + 2);
                        const v2f one2 = {1.f, 1.f};
                        const v2f p01 = __builtin_elementwise_fma(kv01, qv01, one2); // pk
                        const v2f p23 = __builtin_elementwise_fma(kv23, qv23, one2); // pk
                        const float pp0 = p01.x * p01.y;
                        const float pp1 = p23.x * p23.y;
                        const float r   = __builtin_amdgcn_rcpf(pp0 * pp1);          // 1 trans
                        const float r01 = r * pp1;     // = 1/(p0*p1)
                        const float r23 = r * pp0;     // = 1/(p2*p3)
                        const v2f inv01 = {r01 * p01.y, r01 * p01.x};  // (1/p0, 1/p1)
                        const v2f inv23 = {r23 * p23.y, r23 * p23.x};  // (1/p2, 1/p3)
                        acc2[i] = __builtin_elementwise_fma(sv01, inv01, acc2[i]);   // pk
                        acc2[i] = __builtin_elementwise_fma(sv23, inv23, acc2[i]);   // pk
                    }
                }
#pragma unroll
                for (int i = 0; i < 4; ++i) wr[i * Tv + jc] = acc2[i].x + acc2[i].y;
            }
        }
    }
    __syncthreads();

    // ---- softmax, no max pass: wave wv -> row wv>>1, half wv&1 ----
    {
        const int ln = t & 63;
        const int i = wvu >> 1, h = wvu & 1;
        float* __restrict__ row        = w    + i * Tv;
        const float* __restrict__ rowB = pbuf + i * Tv;
        float sum = 0.f;
#pragma unroll
        for (int c = 0; c < 4; ++c) {
            const int e = ln + 64 * (h * 4 + c);
            if (e < cnt) {
                // score - const = -2*(rA+rB); bounded by ~|sum scale| -> safe
                const float ex = __builtin_amdgcn_exp2f(-C2LOG2E * (row[e] + rowB[e]));
                row[e] = ex;
                sum += ex;
            } else {
                row[e] = 0.f;                  // pad for context float4 reads
            }
        }
#pragma unroll
        for (int off = 32; off; off >>= 1) sum += __shfl_xor(sum, off, 64);
        if (ln == 0) sums8[wvu] = sum;         // wvu = 2*i + h
    }
    __syncthreads();

    // ---- context: 4 d's/thread, 4 wave-uniform j-groups, pk_fma ----
    const int g2 = wvu >> 1;                  // 0..3
    const int cc = t & 127;
    const int d0 = cc * 4;
    const int chunk = ((cntp4 + 15) >> 4) << 2;            // 4-aligned quarter
    const int jbeg = g2 * chunk;
    const int jend = min(jbeg + chunk, cntp4);
    const float* __restrict__ vb = value + (size_t)b * Tv * Dd + d0;
    v2f axl[4], axh[4];
#pragma unroll
    for (int i = 0; i < 4; ++i) { axl[i] = (v2f){0.f, 0.f}; axh[i] = (v2f){0.f, 0.f}; }

#pragma unroll 2
    for (int jj = jbeg; jj < jend; jj += 4) {
        const int4 rows = *reinterpret_cast<const int4*>(jl + jj);   // broadcast
        const float4 v0 = *reinterpret_cast<const float4*>(vb + (size_t)rows.x * Dd);
        const float4 v1 = *reinterpret_cast<const float4*>(vb + (size_t)rows.y * Dd);
        const float4 v2 = *reinterpret_cast<const float4*>(vb + (size_t)rows.z * Dd);
        const float4 v3 = *reinterpret_cast<const float4*>(vb + (size_t)rows.w * Dd);
        const v2f v0l = {v0.x, v0.y}, v0h = {v0.z, v0.w};
        const v2f v1l = {v1.x, v1.y}, v1h = {v1.z, v1.w};
        const v2f v2l = {v2.x, v2.y}, v2h = {v2.z, v2.w};
        const v2f v3l = {v3.x, v3.y}, v3h = {v3.z, v3.w};
#pragma unroll
        for (int i = 0; i < 4; ++i) {
            const float4 wq = *reinterpret_cast<const float4*>(w + i * Tv + jj); // broadcast
            const v2f wx = {wq.x, wq.x};
            axl[i] = __builtin_elementwise_fma(wx, v0l, axl[i]);
            axh[i] = __builtin_elementwise_fma(wx, v0h, axh[i]);
            const v2f wy = {wq.y, wq.y};
            axl[i] = __builtin_elementwise_fma(wy, v1l, axl[i]);
            axh[i] = __builtin_elementwise_fma(wy, v1h, axh[i]);
            const v2f wz = {wq.z, wq.z};
            axl[i] = __builtin_elementwise_fma(wz, v2l, axl[i]);
            axh[i] = __builtin_elementwise_fma(wz, v2h, axh[i]);
            const v2f ww = {wq.w, wq.w};
            axl[i] = __builtin_elementwise_fma(ww, v3l, axl[i]);
            axh[i] = __builtin_elementwise_fma(ww, v3h, axh[i]);
        }
    }

    if (g2 != 0) {                            // groups 1..3 park partials
#pragma unroll
        for (int i = 0; i < 4; ++i) {
            const float4 p = make_float4(axl[i].x, axl[i].y, axh[i].x, axh[i].y);
            *reinterpret_cast<float4*>(pbuf + ((size_t)(g2 - 1) * 4 + i) * Dd + d0) = p;
        }
    }
    __syncthreads();
    if (g2 == 0) {                            // group 0 combines + stores
#pragma unroll
        for (int i = 0; i < 4; ++i) {
            const float inv = 1.0f / (sums8[2 * i] + sums8[2 * i + 1]);
            const float4 p1 = *reinterpret_cast<const float4*>(pbuf + ((size_t)0 * 4 + i) * Dd + d0);
            const float4 p2 = *reinterpret_cast<const float4*>(pbuf + ((size_t)1 * 4 + i) * Dd + d0);
            const float4 p3 = *reinterpret_cast<const float4*>(pbuf + ((size_t)2 * 4 + i) * Dd + d0);
            float4 o;
            o.x = (axl[i].x + p1.x + p2.x + p3.x) * inv;
            o.y = (axl[i].y + p1.y + p2.y + p3.y) * inv;
            o.z = (axh[i].x + p1.z + p2.z + p3.z) * inv;
            o.w = (axh[i].y + p1.w + p2.w + p3.w) * inv;
            *reinterpret_cast<float4*>(out + (size_t)(r0 + i) * Dd + d0) = o;
        }
    }
}

extern "C" void kernel_launch(void* const* d_in, const int* in_sizes, int n_in,
                              void* d_out, int out_size, void* d_ws, size_t ws_size,
                              hipStream_t stream)
{
    const float* query = (const float*)d_in[0];
    const float* key   = (const float*)d_in[1];
    const float* value = (const float*)d_in[2];
    const int*   mask  = (const int*)d_in[3];     // proven int32 (R2 bit-identical)
    const float* Wa    = (const float*)d_in[4];
    const float* Ua    = (const float*)d_in[5];
    const float* scale = (const float*)d_in[6];
    float* out = (float*)d_out;

    float* qf2 = (float*)d_ws;                    // [4096,128] = 2 MB (Eq)
    float* kT  = qf2 + Bb * Tq * Uu;              // [8][32][512] float4 = 2 MB (Ek, compact)
    int*   jl_g  = (int*)(kT + Bb * Uu * Tv);     // [8][512] compact index lists
    int*   cnt_g = jl_g + Bb * Tv;                // [8]

    proj_kernel<<<(2 * Bb * Tq) / 8, 512, 0, stream>>>(query, key, Wa, Ua, mask,
                                                       qf2, kT, jl_g, cnt_g);
    attn_kernel<<<(Bb * Tq) / 4, 512, 0, stream>>>(qf2, kT, value, jl_g, cnt_g,
                                                   scale, out);
}

// Round 10
// 138.188 us; speedup vs baseline: 1.1440x; 1.1440x over previous
//
#include <hip/hip_runtime.h>

// Problem constants (B=8, Tq=Tv=512, D=512, U=128)
constexpr int Bb = 8;
constexpr int Tq = 512;
constexpr int Tv = 512;
constexpr int Dd = 512;
constexpr int Uu = 128;
constexpr float C2LOG2E = 2.88539008177792681f;   // 2*log2(e)

typedef float v2f __attribute__((ext_vector_type(2)));

// ---------------------------------------------------------------------------
// Kernel A v10: projections (R6's best-measured s_load body) + V-COMPACTION.
// 8 rows/block, 512 threads, 1024 blocks. x fragments wave-uniform -> s_load
// broadcast; W as float2; 8-way d-partials via LDS. Outputs Eq/Ek =
// exp2(2log2e*proj); kT compact u4-interleaved. NEW: key-blocks also copy
// their masked value rows into vc[b][pos][:] (dense compact V), and the
// j0==0 writer block zeros the <=3 tail rows [cnt, cntp4) so attn's context
// can run dense without the jl indirection. jl_g export removed (dead).
// ---------------------------------------------------------------------------
__global__ __launch_bounds__(512, 8) void proj_kernel(
    const float* __restrict__ query,
    const float* __restrict__ key,
    const float* __restrict__ value,
    const float* __restrict__ Wa,
    const float* __restrict__ Ua,
    const int* __restrict__ mask,
    float* __restrict__ qf2, float* __restrict__ kT,
    float* __restrict__ vc, int* __restrict__ cnt_g)
{
    const int R    = blockIdx.x * 8;               // 0..8191
    const bool isQ = R < Bb * Tq;
    const float* __restrict__ src = isQ ? query : key;
    const float* __restrict__ W   = isQ ? Wa : Ua;
    const int Rloc = isQ ? R : R - Bb * Tq;        // 0..4095

    __shared__ float part[8 * 8 * 128];            // 32 KB: part[dq][r][u]
    __shared__ int posLoc[8];
    __shared__ int cntS;
    const int t = threadIdx.x;

    if (!isQ && t < 64) {                          // wave-0 ballot scan -> pos
        const int b  = Rloc >> 9;
        const int j0 = Rloc & 511;                 // 8-aligned
        const bool writer = (j0 == 0);             // one block per batch exports
        int base = 0;
#pragma unroll
        for (int c = 0; c < 8; ++c) {
            const int j = c * 64 + t;
            const int v = (mask[b * 512 + j] != 0);
            const unsigned long long bits = __ballot(v);
            const int pos = base + (int)__popcll(bits & ((1ull << t) - 1ull));
            if (j >= j0 && j < j0 + 8) posLoc[j - j0] = v ? pos : -1;
            base += (int)__popcll(bits);
        }
        if (writer && t == 0) { cnt_g[b] = base; cntS = base; }
    }

    const int u2 = (t & 63) * 2;                   // adjacent u pair
    const int dq = __builtin_amdgcn_readfirstlane(t >> 6);  // wave's d-eighth
    const float* __restrict__ Wq = W + (size_t)dq * 64 * Uu;
    const float* __restrict__ xs = src + (size_t)Rloc * Dd + dq * 64;  // uniform

    float acc[8][2];
#pragma unroll
    for (int r = 0; r < 8; ++r) { acc[r][0] = 0.f; acc[r][1] = 0.f; }

#pragma unroll 2
    for (int d4 = 0; d4 < 16; ++d4) {
        const int d = d4 * 4;
        const float2 w0 = *reinterpret_cast<const float2*>(Wq + (d + 0) * Uu + u2);
        const float2 w1 = *reinterpret_cast<const float2*>(Wq + (d + 1) * Uu + u2);
        const float2 w2 = *reinterpret_cast<const float2*>(Wq + (d + 2) * Uu + u2);
        const float2 w3 = *reinterpret_cast<const float2*>(Wq + (d + 3) * Uu + u2);
#pragma unroll
        for (int r = 0; r < 8; ++r) {
            // uniform address (block/wave/loop indices only) -> s_load broadcast
            const float4 xv = *reinterpret_cast<const float4*>(xs + r * Dd + d);
            acc[r][0] = fmaf(xv.x, w0.x, acc[r][0]);
            acc[r][1] = fmaf(xv.x, w0.y, acc[r][1]);
            acc[r][0] = fmaf(xv.y, w1.x, acc[r][0]);
            acc[r][1] = fmaf(xv.y, w1.y, acc[r][1]);
            acc[r][0] = fmaf(xv.z, w2.x, acc[r][0]);
            acc[r][1] = fmaf(xv.z, w2.y, acc[r][1]);
            acc[r][0] = fmaf(xv.w, w3.x, acc[r][0]);
            acc[r][1] = fmaf(xv.w, w3.y, acc[r][1]);
        }
    }

    {   // d-partial writes: float2, 2-way bank alias (free)
#pragma unroll
        for (int r = 0; r < 8; ++r) {
            float2 p; p.x = acc[r][0]; p.y = acc[r][1];
            *reinterpret_cast<float2*>(part + (dq * 8 + r) * 128 + u2) = p;
        }
    }
    __syncthreads();

    // reduce 8 d-partials, apply exp2(2log2e * .), store.
    {
        const int r  = t >> 6;
        const int u0 = (t & 63) * 2;
        float s0 = 0.f, s1 = 0.f;
#pragma unroll
        for (int p = 0; p < 8; ++p) {
            const float2 pv = *reinterpret_cast<const float2*>(part + (p * 8 + r) * 128 + u0);
            s0 += pv.x;
            s1 += pv.y;
        }
        float2 e;
        e.x = __builtin_amdgcn_exp2f(C2LOG2E * s0);
        e.y = __builtin_amdgcn_exp2f(C2LOG2E * s1);
        if (isQ) {
            *reinterpret_cast<float2*>(qf2 + (size_t)(Rloc + r) * Uu + u0) = e;
        } else {
            const int p = posLoc[r];
            if (p >= 0) {
                float* __restrict__ kb = kT + (size_t)(Rloc >> 9) * Uu * Tv;
                const int u4 = u0 >> 2;            // quad index
                const int c  = u0 & 3;             // 0 or 2
                *reinterpret_cast<float2*>(kb + ((size_t)u4 * Tv + p) * 4 + c) = e;
            }
        }
    }

    if (!isQ) {
        const int b = Rloc >> 9;
        // compact this block's masked value rows: vc[b][pos][:] = value[row][:]
        {
            const int r  = t >> 6;                 // 0..7
            const int di = t & 63;                 // 0..63
            const int p  = posLoc[r];
            if (p >= 0) {
                const float4* __restrict__ vsrc =
                    reinterpret_cast<const float4*>(value + (size_t)(Rloc + r) * Dd);
                float4* __restrict__ vdst =
                    reinterpret_cast<float4*>(vc + ((size_t)b * Tv + p) * Dd);
                vdst[di]      = vsrc[di];
                vdst[di + 64] = vsrc[di + 64];
            }
        }
        // writer block zeros tail rows [cnt, min(cnt+4,512)) for dense context
        if ((Rloc & 511) == 0) {
            const int cnt = cntS;                  // set before first barrier
            const int zr = t >> 7;                 // 0..3
            const int zd = t & 127;                // 0..127
            if (cnt + zr < 512) {
                float4* __restrict__ vdst =
                    reinterpret_cast<float4*>(vc + ((size_t)b * Tv + cnt + zr) * Dd);
                vdst[zd] = make_float4(0.f, 0.f, 0.f, 0.f);
            }
        }
    }
}

// ---------------------------------------------------------------------------
// Kernel B v9: attention, 8 q-rows/block, 1024 threads, 512 blocks
// (2 blocks/CU x 16 waves = 32 waves/CU -- full occupancy kept while value/kT
// L2 traffic HALVES vs the 4-row structure). Bijective XCD swizzle.
//   score  : u split into 4 QUARTERS across wave-groups g=wvu>>2; each group's
//            4 waves cover 256 compact-j lanes; partials -> wbuf[g] (4x16KB).
//            pk-fp32 + quad-rcp; q/scale via s_load (uniform).
//   softmax: no max pass; wave wv -> (row wv>>1, half wv&1); combines the 4
//            u-quarter partials; weights land in wbuf[0], zero-padded.
//   context: DENSE compact V (vc) -- no jl indirection; 4 wave-uniform
//            j-groups, 2 d's/thread (v2f pk_fma); partials parked in
//            wbuf[1..3], group 0 combines + stores.
// ---------------------------------------------------------------------------
__global__ __launch_bounds__(1024, 8) void attn_kernel(
    const float* __restrict__ qf2, const float* __restrict__ kT,
    const float* __restrict__ vc,
    const int* __restrict__ cnt_g,
    const float* __restrict__ scale,
    float* __restrict__ out)
{
    // XCD-aware bijective swizzle (512 % 8 == 0): XCD x <-> batch x
    const int bid = blockIdx.x;
    const int swz = (bid & 7) * 64 + (bid >> 3);
    const int r0 = swz * 8;                   // first query row (0..4088)
    const int b  = r0 >> 9;
    const int t  = threadIdx.x;               // 0..1023

    __shared__ float wbuf[4][8 * Tv];         // 64 KB: score quarters / weights+parks
    __shared__ float sums16[16];              // per (row, half) exp-sums

    const int cnt = cnt_g[b];                 // uniform -> s_load
    const int wvu = __builtin_amdgcn_readfirstlane(t >> 6); // wave id 0..15
    const int cntp4 = (cnt + 3) & ~3;

    // ---- scores: 4 u-quarter wave-groups x 256 compact-j lanes ----
    {
        const int g   = wvu >> 2;             // u-quarter 0..3
        const int jc0 = t & 255;
        const float* __restrict__ qs = qf2 + (size_t)r0 * Uu + g * 32;  // uniform
        const float* __restrict__ ss = scale + g * 32;                  // uniform
        const float4* __restrict__ kb4 =
            reinterpret_cast<const float4*>(kT) + (size_t)b * 32 * Tv + (size_t)g * 8 * Tv;
        float* __restrict__ wr = wbuf[g];
        for (int jb = 0; jb < cnt; jb += 256) {
            const int jc = jb + jc0;
            if (jc < cnt) {
                v2f acc2[8];
#pragma unroll
                for (int i = 0; i < 8; ++i) acc2[i] = (v2f){0.f, 0.f};
#pragma unroll 2
                for (int u4 = 0; u4 < 8; ++u4) {
                    const float4 kv = kb4[(size_t)u4 * Tv + jc];
                    const v2f kv01 = {kv.x, kv.y};
                    const v2f kv23 = {kv.z, kv.w};
                    const v2f sv01 = *reinterpret_cast<const v2f*>(ss + u4 * 4);
                    const v2f sv23 = *reinterpret_cast<const v2f*>(ss + u4 * 4 + 2);
#pragma unroll
                    for (int i = 0; i < 8; ++i) {
                        const v2f qv01 = *reinterpret_cast<const v2f*>(qs + i * Uu + u4 * 4);
                        const v2f qv23 = *reinterpret_cast<const v2f*>(qs + i * Uu + u4 * 4 + 2);
                        const v2f one2 = {1.f, 1.f};
                        const v2f p01 = __builtin_elementwise_fma(kv01, qv01, one2); // pk
                        const v2f p23 = __builtin_elementwise_fma(kv23, qv23, one2); // pk
                        const float pp0 = p01.x * p01.y;
                        const float pp1 = p23.x * p23.y;
                        const float r   = __builtin_amdgcn_rcpf(pp0 * pp1);          // 1 trans
                        const float r01 = r * pp1;     // = 1/(p0*p1)
                        const float r23 = r * pp0;     // = 1/(p2*p3)
                        const v2f inv01 = {r01 * p01.y, r01 * p01.x};  // (1/p0, 1/p1)
                        const v2f inv23 = {r23 * p23.y, r23 * p23.x};  // (1/p2, 1/p3)
                        acc2[i] = __builtin_elementwise_fma(sv01, inv01, acc2[i]);   // pk
                        acc2[i] = __builtin_elementwise_fma(sv23, inv23, acc2[i]);   // pk
                    }
                }
#pragma unroll
                for (int i = 0; i < 8; ++i) wr[i * Tv + jc] = acc2[i].x + acc2[i].y;
            }
        }
    }
    __syncthreads();

    // ---- softmax, no max pass: wave wv -> row wv>>1, half wv&1 ----
    {
        const int ln = t & 63;
        const int i = wvu >> 1, h = wvu & 1;
        float* __restrict__ row        = wbuf[0] + i * Tv;
        const float* __restrict__ rowB = wbuf[1] + i * Tv;
        const float* __restrict__ rowC = wbuf[2] + i * Tv;
        const float* __restrict__ rowD = wbuf[3] + i * Tv;
        float sum = 0.f;
#pragma unroll
        for (int c = 0; c < 4; ++c) {
            const int e = ln + 64 * (h * 4 + c);
            if (e < cnt) {
                // score - const = -2*(sum of 4 quarter-partials); bounded -> safe
                const float ex = __builtin_amdgcn_exp2f(
                    -C2LOG2E * (row[e] + rowB[e] + rowC[e] + rowD[e]));
                row[e] = ex;
                sum += ex;
            } else {
                row[e] = 0.f;                  // pad for context float4 reads
            }
        }
#pragma unroll
        for (int off = 32; off; off >>= 1) sum += __shfl_xor(sum, off, 64);
        if (ln == 0) sums16[wvu] = sum;        // wvu = 2*i + h
    }
    __syncthreads();

    // ---- context: DENSE compact V, 4 wave-uniform j-groups, 2 d's/thread ----
    const int g2 = wvu >> 2;                  // 0..3
    const int c  = t & 255;
    const int d0 = c * 2;
    const int chunk = ((cntp4 + 15) >> 4) << 2;            // 4-aligned quarter
    const int jbeg = g2 * chunk;
    const int jend = min(jbeg + chunk, cntp4);
    const float* __restrict__ vb = vc + (size_t)b * Tv * Dd + d0;
    v2f ax[8];
#pragma unroll
    for (int i = 0; i < 8; ++i) ax[i] = (v2f){0.f, 0.f};

#pragma unroll 2
    for (int jj = jbeg; jj < jend; jj += 4) {
        const v2f v0 = *reinterpret_cast<const v2f*>(vb + (size_t)(jj + 0) * Dd);
        const v2f v1 = *reinterpret_cast<const v2f*>(vb + (size_t)(jj + 1) * Dd);
        const v2f v2 = *reinterpret_cast<const v2f*>(vb + (size_t)(jj + 2) * Dd);
        const v2f v3 = *reinterpret_cast<const v2f*>(vb + (size_t)(jj + 3) * Dd);
#pragma unroll
        for (int i = 0; i < 8; ++i) {
            const float4 wq = *reinterpret_cast<const float4*>(wbuf[0] + i * Tv + jj); // broadcast
            ax[i] = __builtin_elementwise_fma((v2f){wq.x, wq.x}, v0, ax[i]);
            ax[i] = __builtin_elementwise_fma((v2f){wq.y, wq.y}, v1, ax[i]);
            ax[i] = __builtin_elementwise_fma((v2f){wq.z, wq.z}, v2, ax[i]);
            ax[i] = __builtin_elementwise_fma((v2f){wq.w, wq.w}, v3, ax[i]);
        }
    }

    if (g2 != 0) {                            // groups 1..3 park partials
#pragma unroll
        for (int i = 0; i < 8; ++i)
            *reinterpret_cast<v2f*>(wbuf[g2] + i * Tv + d0) = ax[i];
    }
    __syncthreads();
    if (g2 == 0) {                            // group 0 combines + stores
#pragma unroll
        for (int i = 0; i < 8; ++i) {
            const float inv = 1.0f / (sums16[2 * i] + sums16[2 * i + 1]);
            const v2f p1 = *reinterpret_cast<const v2f*>(wbuf[1] + i * Tv + d0);
            const v2f p2 = *reinterpret_cast<const v2f*>(wbuf[2] + i * Tv + d0);
            const v2f p3 = *reinterpret_cast<const v2f*>(wbuf[3] + i * Tv + d0);
            float2 o;
            o.x = (ax[i].x + p1.x + p2.x + p3.x) * inv;
            o.y = (ax[i].y + p1.y + p2.y + p3.y) * inv;
            *reinterpret_cast<float2*>(out + (size_t)(r0 + i) * Dd + d0) = o;
        }
    }
}

extern "C" void kernel_launch(void* const* d_in, const int* in_sizes, int n_in,
                              void* d_out, int out_size, void* d_ws, size_t ws_size,
                              hipStream_t stream)
{
    const float* query = (const float*)d_in[0];
    const float* key   = (const float*)d_in[1];
    const float* value = (const float*)d_in[2];
    const int*   mask  = (const int*)d_in[3];     // proven int32 (R2 bit-identical)
    const float* Wa    = (const float*)d_in[4];
    const float* Ua    = (const float*)d_in[5];
    const float* scale = (const float*)d_in[6];
    float* out = (float*)d_out;

    float* qf2   = (float*)d_ws;                  // [4096,128] = 2 MB (Eq)
    float* kT    = qf2 + Bb * Tq * Uu;            // [8][32][512] float4 = 2 MB (Ek)
    float* vc    = kT + Bb * Uu * Tv;             // [8][512][512] = 8 MB (compact V)
    int*   cnt_g = (int*)(vc + (size_t)Bb * Tv * Dd);  // [8]

    proj_kernel<<<(2 * Bb * Tq) / 8, 512, 0, stream>>>(query, key, value, Wa, Ua,
                                                       mask, qf2, kT, vc, cnt_g);
    attn_kernel<<<(Bb * Tq) / 8, 1024, 0, stream>>>(qf2, kT, vc, cnt_g, scale, out);
}